// Round 2
// baseline (773.639 us; speedup 1.0000x reference)
//
#include <hip/hip_runtime.h>

#define C_ 64
#define H_ 128
#define W_ 128
#define B_ 8
#define HW_ (H_*W_)
#define NPIX (B_*HW_)

// ---------------------------------------------------------------------------
// Kernel A: fused offset/mask convs for both passes + weight transposes.
// Block = 256 threads = 4 waves x 64 pixels. Wave w handles input channels
// [16w, 16w+16); partial 18-vector accumulators reduced via LDS.
// ---------------------------------------------------------------------------
__global__ __launch_bounds__(256) void offs_kernel(
    const float* __restrict__ x,
    const float* __restrict__ w_off_h, const float* __restrict__ b_off_h,
    const float* __restrict__ w_mask_h, const float* __restrict__ b_mask_h,
    const float* __restrict__ w_off_v, const float* __restrict__ b_off_v,
    const float* __restrict__ w_mask_v, const float* __restrict__ b_mask_v,
    const float* __restrict__ w_h, const float* __restrict__ w_v,
    float* __restrict__ off_h, float* __restrict__ mask_h,
    float* __restrict__ off_v, float* __restrict__ mask_v,
    float* __restrict__ wT_h, float* __restrict__ wT_v)
{
    int gid = blockIdx.x * 256 + threadIdx.x;

    // Weight transpose: wT[c*192 + k*64 + o] = w[o*192 + c*3 + k]
    if (gid < 2 * 12288) {
        int which = gid / 12288;
        int idx = gid - which * 12288;
        int o = idx & 63;
        int ck = idx >> 6;
        int c = ck / 3;
        int k = ck - 3 * c;
        const float* srcw = which ? w_v : w_h;
        float* dstw = which ? wT_v : wT_h;
        dstw[idx] = srcw[o * 192 + c * 3 + k];
    }

    int lane = threadIdx.x & 63;
    int wv   = threadIdx.x >> 6;      // channel slice 0..3
    int p = blockIdx.x * 64 + lane;   // 64 consecutive pixels per block
    int j = p & (W_ - 1);
    int i = (p >> 7) & (H_ - 1);
    int n = p >> 14;
    int pix = i * W_ + j;

    float a[18];
    #pragma unroll
    for (int o = 0; o < 18; ++o) a[o] = 0.f;

    int c0 = wv * 16;
    const float* xb = x + (size_t)n * C_ * HW_ + (size_t)c0 * HW_;
    for (int cc = 0; cc < 16; ++cc) {
        int c = c0 + cc;              // wave-uniform -> scalar weight loads
        const float* s = xb + cc * HW_;
        float xc = s[pix];
        float xl = (j > 0)      ? s[pix - 1]  : 0.f;
        float xr = (j < W_ - 1) ? s[pix + 1]  : 0.f;
        float xu = (i > 0)      ? s[pix - W_] : 0.f;
        float xd = (i < H_ - 1) ? s[pix + W_] : 0.f;
        const float* wh = w_off_h  + c * 3;
        const float* wm = w_mask_h + c * 3;
        const float* wn = w_off_v  + c * 3;
        const float* wq = w_mask_v + c * 3;
        #pragma unroll
        for (int o = 0; o < 6; ++o) {
            a[o]   = fmaf(xl, wh[o*192+0], fmaf(xc, wh[o*192+1], fmaf(xr, wh[o*192+2], a[o])));
            a[9+o] = fmaf(xu, wn[o*192+0], fmaf(xc, wn[o*192+1], fmaf(xd, wn[o*192+2], a[9+o])));
        }
        #pragma unroll
        for (int o = 0; o < 3; ++o) {
            a[6+o]  = fmaf(xl, wm[o*192+0], fmaf(xc, wm[o*192+1], fmaf(xr, wm[o*192+2], a[6+o])));
            a[15+o] = fmaf(xu, wq[o*192+0], fmaf(xc, wq[o*192+1], fmaf(xd, wq[o*192+2], a[15+o])));
        }
    }

    // Cross-wave reduction: [slice][idx][px], px=lane consecutive -> no conflicts
    __shared__ float red[4][18][64];
    #pragma unroll
    for (int o = 0; o < 18; ++o) red[wv][o][lane] = a[o];
    __syncthreads();

    for (int v = threadIdx.x; v < 18 * 64; v += 256) {
        int idx = v >> 6;
        int px  = v & 63;
        float sum = red[0][idx][px] + red[1][idx][px]
                  + red[2][idx][px] + red[3][idx][px];
        int pg  = blockIdx.x * 64 + px;
        int nn  = pg >> 14;
        int pixg = pg & (HW_ - 1);
        if (idx < 6) {
            sum += b_off_h[idx];
            off_h[((size_t)nn * 6 + idx) * HW_ + pixg] = sum;
        } else if (idx < 9) {
            sum += b_mask_h[idx - 6];
            mask_h[((size_t)nn * 3 + (idx - 6)) * HW_ + pixg] = 1.f / (1.f + __expf(-sum));
        } else if (idx < 15) {
            sum += b_off_v[idx - 9];
            off_v[((size_t)nn * 6 + (idx - 9)) * HW_ + pixg] = sum;
        } else {
            sum += b_mask_v[idx - 15];
            mask_v[((size_t)nn * 3 + (idx - 15)) * HW_ + pixg] = 1.f / (1.f + __expf(-sum));
        }
    }
}

// ---------------------------------------------------------------------------
// Kernel B/C: deformable axial conv pass.
// Block = 256 threads = 4 waves x 64 pixels. Wave w accumulates input
// channels [16w,16w+16) into 64 output partials (weights stay wave-uniform
// -> scalar loads; each channel sampled exactly once). Partials reduced
// across the 4 waves via 16KB LDS in four 16-output chunks.
// ---------------------------------------------------------------------------
__global__ __launch_bounds__(256) void deform_kernel(
    const float* __restrict__ src, const float* __restrict__ off,
    const float* __restrict__ mask, const float* __restrict__ wT,
    const float* __restrict__ bias, float* __restrict__ out, int axis)
{
    int lane = threadIdx.x & 63;
    int wv   = threadIdx.x >> 6;      // channel slice 0..3
    int p = blockIdx.x * 64 + lane;
    int j = p & (W_ - 1);
    int i = (p >> 7) & (H_ - 1);
    int n = p >> 14;
    int pix = i * W_ + j;

    int a00[3], a01[3], a10[3], a11[3];
    float w00[3], w01[3], w10[3], w11[3];

    #pragma unroll
    for (int k = 0; k < 3; ++k) {
        float dy = off[(((size_t)n * 3 + k) * 2 + 0) * HW_ + pix];
        float dx = off[(((size_t)n * 3 + k) * 2 + 1) * HW_ + pix];
        float m  = mask[((size_t)n * 3 + k) * HW_ + pix];
        float py = (float)i + dy + (axis ? (float)(k - 1) : 0.f);
        float px = (float)j + dx + (axis ? 0.f : (float)(k - 1));
        float y0f = floorf(py), x0f = floorf(px);
        float wy = py - y0f, wx = px - x0f;
        int y0 = (int)y0f, x0 = (int)x0f;
        int y1 = y0 + 1, x1 = x0 + 1;
        bool vy0 = (y0 >= 0) && (y0 < H_);
        bool vy1 = (y1 >= 0) && (y1 < H_);
        bool vx0 = (x0 >= 0) && (x0 < W_);
        bool vx1 = (x1 >= 0) && (x1 < W_);
        int y0c = min(max(y0, 0), H_ - 1), y1c = min(max(y1, 0), H_ - 1);
        int x0c = min(max(x0, 0), W_ - 1), x1c = min(max(x1, 0), W_ - 1);
        a00[k] = y0c * W_ + x0c;  a01[k] = y0c * W_ + x1c;
        a10[k] = y1c * W_ + x0c;  a11[k] = y1c * W_ + x1c;
        float wy1 = 1.f - wy, wx1 = 1.f - wx;
        w00[k] = (vy0 && vx0) ? wy1 * wx1 * m : 0.f;
        w01[k] = (vy0 && vx1) ? wy1 * wx  * m : 0.f;
        w10[k] = (vy1 && vx0) ? wy  * wx1 * m : 0.f;
        w11[k] = (vy1 && vx1) ? wy  * wx  * m : 0.f;
    }

    float acc[64];
    #pragma unroll
    for (int o = 0; o < 64; ++o) acc[o] = 0.f;

    int c0 = wv * 16;
    const float* sb = src + (size_t)n * C_ * HW_ + (size_t)c0 * HW_;
    const float* wp = wT + c0 * 192;
    for (int cc = 0; cc < 16; ++cc) {
        const float* s = sb + cc * HW_;
        float vk[3];
        #pragma unroll
        for (int k = 0; k < 3; ++k) {
            vk[k] = fmaf(w00[k], s[a00[k]],
                    fmaf(w01[k], s[a01[k]],
                    fmaf(w10[k], s[a10[k]],
                         w11[k] * s[a11[k]])));
        }
        const float* wr = wp + cc * 192;   // wave-uniform -> s_load
        #pragma unroll
        for (int o = 0; o < 64; ++o) {
            acc[o] = fmaf(vk[0], wr[o],
                     fmaf(vk[1], wr[64 + o],
                     fmaf(vk[2], wr[128 + o], acc[o])));
        }
    }

    // Cross-wave reduction in 4 chunks of 16 outputs (16 KB LDS).
    __shared__ float red[4][16][64];
    #pragma unroll 1
    for (int q = 0; q < 4; ++q) {
        if (q) __syncthreads();
        #pragma unroll
        for (int o = 0; o < 16; ++o) red[wv][o][lane] = acc[q * 16 + o];
        __syncthreads();
        #pragma unroll
        for (int k = 0; k < 4; ++k) {
            int v = threadIdx.x + k * 256;   // 0..1023
            int o = v >> 6;                  // 0..15
            int px = v & 63;
            float sum = red[0][o][px] + red[1][o][px]
                      + red[2][o][px] + red[3][o][px];
            int oo = q * 16 + o;
            int pg = blockIdx.x * 64 + px;
            int nn = pg >> 14;
            int pixg = pg & (HW_ - 1);
            out[((size_t)nn * C_ + oo) * HW_ + pixg] = sum + bias[oo];
        }
    }
}

// ---------------------------------------------------------------------------
extern "C" void kernel_launch(void* const* d_in, const int* in_sizes, int n_in,
                              void* d_out, int out_size, void* d_ws, size_t ws_size,
                              hipStream_t stream)
{
    const float* x        = (const float*)d_in[0];
    const float* w_off_h  = (const float*)d_in[1];
    const float* b_off_h  = (const float*)d_in[2];
    const float* w_mask_h = (const float*)d_in[3];
    const float* b_mask_h = (const float*)d_in[4];
    const float* w_off_v  = (const float*)d_in[5];
    const float* b_off_v  = (const float*)d_in[6];
    const float* w_mask_v = (const float*)d_in[7];
    const float* b_mask_v = (const float*)d_in[8];
    const float* w_h      = (const float*)d_in[9];
    const float* b_h      = (const float*)d_in[10];
    const float* w_v      = (const float*)d_in[11];
    const float* b_v      = (const float*)d_in[12];

    float* ws     = (float*)d_ws;
    float* off_h  = ws;                   // 786432
    float* mask_h = off_h  + 786432;      // 393216
    float* off_v  = mask_h + 393216;      // 786432
    float* mask_v = off_v  + 786432;      // 393216
    float* x_h    = mask_v + 393216;      // 8388608
    float* wT_h   = x_h    + 8388608;     // 12288
    float* wT_v   = wT_h   + 12288;       // 12288

    dim3 grid(NPIX / 64), block(256);     // 4 waves per 64-pixel group
    offs_kernel<<<grid, block, 0, stream>>>(x,
        w_off_h, b_off_h, w_mask_h, b_mask_h,
        w_off_v, b_off_v, w_mask_v, b_mask_v,
        w_h, w_v,
        off_h, mask_h, off_v, mask_v, wT_h, wT_v);

    deform_kernel<<<grid, block, 0, stream>>>(x,   off_h, mask_h, wT_h, b_h, x_h,          0);
    deform_kernel<<<grid, block, 0, stream>>>(x_h, off_v, mask_v, wT_v, b_v, (float*)d_out, 1);
}

// Round 3
// 693.670 us; speedup vs baseline: 1.1153x; 1.1153x over previous
//
#include <hip/hip_runtime.h>

#define C_ 64
#define H_ 128
#define W_ 128
#define B_ 8
#define HW_ (H_*W_)
#define NPIX (B_*HW_)

// ---------------------------------------------------------------------------
// Kernel A: fused offset/mask convs for both passes + weight transposes.
// Block = 256 threads = 4 waves x 64 pixels. Wave w handles input channels
// [16w, 16w+16); partial 18-vector accumulators reduced via LDS.
// ---------------------------------------------------------------------------
__global__ __launch_bounds__(256) void offs_kernel(
    const float* __restrict__ x,
    const float* __restrict__ w_off_h, const float* __restrict__ b_off_h,
    const float* __restrict__ w_mask_h, const float* __restrict__ b_mask_h,
    const float* __restrict__ w_off_v, const float* __restrict__ b_off_v,
    const float* __restrict__ w_mask_v, const float* __restrict__ b_mask_v,
    const float* __restrict__ w_h, const float* __restrict__ w_v,
    float* __restrict__ off_h, float* __restrict__ mask_h,
    float* __restrict__ off_v, float* __restrict__ mask_v,
    float* __restrict__ wT_h, float* __restrict__ wT_v)
{
    int gid = blockIdx.x * 256 + threadIdx.x;

    // Weight transpose: wT[c*192 + k*64 + o] = w[o*192 + c*3 + k]
    if (gid < 2 * 12288) {
        int which = gid / 12288;
        int idx = gid - which * 12288;
        int o = idx & 63;
        int ck = idx >> 6;
        int c = ck / 3;
        int k = ck - 3 * c;
        const float* srcw = which ? w_v : w_h;
        float* dstw = which ? wT_v : wT_h;
        dstw[idx] = srcw[o * 192 + c * 3 + k];
    }

    int lane = threadIdx.x & 63;
    int wv   = threadIdx.x >> 6;      // channel slice 0..3
    int p = blockIdx.x * 64 + lane;   // 64 consecutive pixels per block
    int j = p & (W_ - 1);
    int i = (p >> 7) & (H_ - 1);
    int n = p >> 14;
    int pix = i * W_ + j;

    float a[18];
    #pragma unroll
    for (int o = 0; o < 18; ++o) a[o] = 0.f;

    int c0 = wv * 16;
    const float* xb = x + (size_t)n * C_ * HW_ + (size_t)c0 * HW_;
    for (int cc = 0; cc < 16; ++cc) {
        int c = c0 + cc;              // wave-uniform -> scalar weight loads
        const float* s = xb + cc * HW_;
        float xc = s[pix];
        float xl = (j > 0)      ? s[pix - 1]  : 0.f;
        float xr = (j < W_ - 1) ? s[pix + 1]  : 0.f;
        float xu = (i > 0)      ? s[pix - W_] : 0.f;
        float xd = (i < H_ - 1) ? s[pix + W_] : 0.f;
        const float* wh = w_off_h  + c * 3;
        const float* wm = w_mask_h + c * 3;
        const float* wn = w_off_v  + c * 3;
        const float* wq = w_mask_v + c * 3;
        #pragma unroll
        for (int o = 0; o < 6; ++o) {
            a[o]   = fmaf(xl, wh[o*192+0], fmaf(xc, wh[o*192+1], fmaf(xr, wh[o*192+2], a[o])));
            a[9+o] = fmaf(xu, wn[o*192+0], fmaf(xc, wn[o*192+1], fmaf(xd, wn[o*192+2], a[9+o])));
        }
        #pragma unroll
        for (int o = 0; o < 3; ++o) {
            a[6+o]  = fmaf(xl, wm[o*192+0], fmaf(xc, wm[o*192+1], fmaf(xr, wm[o*192+2], a[6+o])));
            a[15+o] = fmaf(xu, wq[o*192+0], fmaf(xc, wq[o*192+1], fmaf(xd, wq[o*192+2], a[15+o])));
        }
    }

    // Cross-wave reduction: [slice][idx][px], px=lane consecutive -> no conflicts
    __shared__ float red[4][18][64];
    #pragma unroll
    for (int o = 0; o < 18; ++o) red[wv][o][lane] = a[o];
    __syncthreads();

    for (int v = threadIdx.x; v < 18 * 64; v += 256) {
        int idx = v >> 6;
        int px  = v & 63;
        float sum = red[0][idx][px] + red[1][idx][px]
                  + red[2][idx][px] + red[3][idx][px];
        int pg  = blockIdx.x * 64 + px;
        int nn  = pg >> 14;
        int pixg = pg & (HW_ - 1);
        if (idx < 6) {
            sum += b_off_h[idx];
            off_h[((size_t)nn * 6 + idx) * HW_ + pixg] = sum;
        } else if (idx < 9) {
            sum += b_mask_h[idx - 6];
            mask_h[((size_t)nn * 3 + (idx - 6)) * HW_ + pixg] = 1.f / (1.f + __expf(-sum));
        } else if (idx < 15) {
            sum += b_off_v[idx - 9];
            off_v[((size_t)nn * 6 + (idx - 9)) * HW_ + pixg] = sum;
        } else {
            sum += b_mask_v[idx - 15];
            mask_v[((size_t)nn * 3 + (idx - 15)) * HW_ + pixg] = 1.f / (1.f + __expf(-sum));
        }
    }
}

// ---------------------------------------------------------------------------
// Kernel B/C: deformable axial conv pass.
// Block = 256 threads = 4 waves x 64 pixels. Wave w accumulates input
// channels [16w,16w+16) into 64 output partials (weights wave-uniform ->
// scalar loads; each (pixel,channel) sampled exactly once). Partials
// reduced across the 4 waves via 16KB LDS in four FULLY-UNROLLED chunks —
// acc[] must only ever see compile-time indices or it demotes to scratch
// (round-2 lesson: runtime index -> 8.4 GB scratch traffic, 4x slowdown).
// ---------------------------------------------------------------------------
__global__ __launch_bounds__(256) void deform_kernel(
    const float* __restrict__ src, const float* __restrict__ off,
    const float* __restrict__ mask, const float* __restrict__ wT,
    const float* __restrict__ bias, float* __restrict__ out, int axis)
{
    int lane = threadIdx.x & 63;
    int wv   = threadIdx.x >> 6;      // channel slice 0..3
    int p = blockIdx.x * 64 + lane;
    int j = p & (W_ - 1);
    int i = (p >> 7) & (H_ - 1);
    int n = p >> 14;
    int pix = i * W_ + j;

    int a00[3], a01[3], a10[3], a11[3];
    float w00[3], w01[3], w10[3], w11[3];

    #pragma unroll
    for (int k = 0; k < 3; ++k) {
        float dy = off[(((size_t)n * 3 + k) * 2 + 0) * HW_ + pix];
        float dx = off[(((size_t)n * 3 + k) * 2 + 1) * HW_ + pix];
        float m  = mask[((size_t)n * 3 + k) * HW_ + pix];
        float py = (float)i + dy + (axis ? (float)(k - 1) : 0.f);
        float px = (float)j + dx + (axis ? 0.f : (float)(k - 1));
        float y0f = floorf(py), x0f = floorf(px);
        float wy = py - y0f, wx = px - x0f;
        int y0 = (int)y0f, x0 = (int)x0f;
        int y1 = y0 + 1, x1 = x0 + 1;
        bool vy0 = (y0 >= 0) && (y0 < H_);
        bool vy1 = (y1 >= 0) && (y1 < H_);
        bool vx0 = (x0 >= 0) && (x0 < W_);
        bool vx1 = (x1 >= 0) && (x1 < W_);
        int y0c = min(max(y0, 0), H_ - 1), y1c = min(max(y1, 0), H_ - 1);
        int x0c = min(max(x0, 0), W_ - 1), x1c = min(max(x1, 0), W_ - 1);
        a00[k] = y0c * W_ + x0c;  a01[k] = y0c * W_ + x1c;
        a10[k] = y1c * W_ + x0c;  a11[k] = y1c * W_ + x1c;
        float wy1 = 1.f - wy, wx1 = 1.f - wx;
        w00[k] = (vy0 && vx0) ? wy1 * wx1 * m : 0.f;
        w01[k] = (vy0 && vx1) ? wy1 * wx  * m : 0.f;
        w10[k] = (vy1 && vx0) ? wy  * wx1 * m : 0.f;
        w11[k] = (vy1 && vx1) ? wy  * wx  * m : 0.f;
    }

    float acc[64];
    #pragma unroll
    for (int o = 0; o < 64; ++o) acc[o] = 0.f;

    int c0 = wv * 16;
    const float* sb = src + (size_t)n * C_ * HW_ + (size_t)c0 * HW_;
    const float* wp = wT + c0 * 192;
    for (int cc = 0; cc < 16; ++cc) {
        const float* s = sb + cc * HW_;
        float vk[3];
        #pragma unroll
        for (int k = 0; k < 3; ++k) {
            vk[k] = fmaf(w00[k], s[a00[k]],
                    fmaf(w01[k], s[a01[k]],
                    fmaf(w10[k], s[a10[k]],
                         w11[k] * s[a11[k]])));
        }
        const float* wr = wp + cc * 192;   // wave-uniform -> s_load
        #pragma unroll
        for (int o = 0; o < 64; ++o) {
            acc[o] = fmaf(vk[0], wr[o],
                     fmaf(vk[1], wr[64 + o],
                     fmaf(vk[2], wr[128 + o], acc[o])));
        }
    }

    // Cross-wave reduction in 4 chunks of 16 outputs (16 KB LDS).
    // Q is a compile-time constant in every chunk -> acc stays in registers.
    __shared__ float red[4][16][64];
    int pg = blockIdx.x * 64;
    int nn = pg >> 14;
    int pixg0 = pg & (HW_ - 1);

#define REDUCE_CHUNK(Q)                                                     \
    {                                                                       \
        if ((Q) > 0) __syncthreads();                                       \
        _Pragma("unroll")                                                   \
        for (int o = 0; o < 16; ++o) red[wv][o][lane] = acc[(Q) * 16 + o];  \
        __syncthreads();                                                    \
        _Pragma("unroll")                                                   \
        for (int k = 0; k < 4; ++k) {                                       \
            int v = threadIdx.x + k * 256;                                  \
            int o = v >> 6;                                                 \
            int px = v & 63;                                                \
            float sum = red[0][o][px] + red[1][o][px]                       \
                      + red[2][o][px] + red[3][o][px];                      \
            int oo = (Q) * 16 + o;                                          \
            out[((size_t)nn * C_ + oo) * HW_ + pixg0 + px] = sum + bias[oo];\
        }                                                                   \
    }

    REDUCE_CHUNK(0)
    REDUCE_CHUNK(1)
    REDUCE_CHUNK(2)
    REDUCE_CHUNK(3)
#undef REDUCE_CHUNK
}

// ---------------------------------------------------------------------------
extern "C" void kernel_launch(void* const* d_in, const int* in_sizes, int n_in,
                              void* d_out, int out_size, void* d_ws, size_t ws_size,
                              hipStream_t stream)
{
    const float* x        = (const float*)d_in[0];
    const float* w_off_h  = (const float*)d_in[1];
    const float* b_off_h  = (const float*)d_in[2];
    const float* w_mask_h = (const float*)d_in[3];
    const float* b_mask_h = (const float*)d_in[4];
    const float* w_off_v  = (const float*)d_in[5];
    const float* b_off_v  = (const float*)d_in[6];
    const float* w_mask_v = (const float*)d_in[7];
    const float* b_mask_v = (const float*)d_in[8];
    const float* w_h      = (const float*)d_in[9];
    const float* b_h      = (const float*)d_in[10];
    const float* w_v      = (const float*)d_in[11];
    const float* b_v      = (const float*)d_in[12];

    float* ws     = (float*)d_ws;
    float* off_h  = ws;                   // 786432
    float* mask_h = off_h  + 786432;      // 393216
    float* off_v  = mask_h + 393216;      // 786432
    float* mask_v = off_v  + 786432;      // 393216
    float* x_h    = mask_v + 393216;      // 8388608
    float* wT_h   = x_h    + 8388608;     // 12288
    float* wT_v   = wT_h   + 12288;       // 12288

    dim3 grid(NPIX / 64), block(256);     // 4 waves per 64-pixel group
    offs_kernel<<<grid, block, 0, stream>>>(x,
        w_off_h, b_off_h, w_mask_h, b_mask_h,
        w_off_v, b_off_v, w_mask_v, b_mask_v,
        w_h, w_v,
        off_h, mask_h, off_v, mask_v, wT_h, wT_v);

    deform_kernel<<<grid, block, 0, stream>>>(x,   off_h, mask_h, wT_h, b_h, x_h,          0);
    deform_kernel<<<grid, block, 0, stream>>>(x_h, off_v, mask_v, wT_v, b_v, (float*)d_out, 1);
}

// Round 4
// 285.317 us; speedup vs baseline: 2.7115x; 2.4312x over previous
//
#include <hip/hip_runtime.h>

#define C_ 64
#define H_ 128
#define W_ 128
#define B_ 8
#define HW_ (H_*W_)
#define NPIX (B_*HW_)

// ---------------------------------------------------------------------------
// Kernel A: fused offset/mask convs for both passes + weight transposes.
// Block = 256 threads = 4 waves x 64 pixels. Wave w handles input channels
// [16w, 16w+16); partial 18-vector accumulators reduced via LDS.
// c0 forced into SGPR via readfirstlane so weight reads stay s_load.
// ---------------------------------------------------------------------------
__global__ __launch_bounds__(256) void offs_kernel(
    const float* __restrict__ x,
    const float* __restrict__ w_off_h, const float* __restrict__ b_off_h,
    const float* __restrict__ w_mask_h, const float* __restrict__ b_mask_h,
    const float* __restrict__ w_off_v, const float* __restrict__ b_off_v,
    const float* __restrict__ w_mask_v, const float* __restrict__ b_mask_v,
    const float* __restrict__ w_h, const float* __restrict__ w_v,
    float* __restrict__ off_h, float* __restrict__ mask_h,
    float* __restrict__ off_v, float* __restrict__ mask_v,
    float* __restrict__ wT_h, float* __restrict__ wT_v)
{
    int gid = blockIdx.x * 256 + threadIdx.x;

    // Weight transpose: wT[c*192 + k*64 + o] = w[o*192 + c*3 + k]
    if (gid < 2 * 12288) {
        int which = gid / 12288;
        int idx = gid - which * 12288;
        int o = idx & 63;
        int ck = idx >> 6;
        int c = ck / 3;
        int k = ck - 3 * c;
        const float* srcw = which ? w_v : w_h;
        float* dstw = which ? wT_v : wT_h;
        dstw[idx] = srcw[o * 192 + c * 3 + k];
    }

    int lane = threadIdx.x & 63;
    int wv   = threadIdx.x >> 6;      // channel slice 0..3
    // Force wave-uniform slice base into an SGPR: without this the compiler
    // can't prove (threadIdx.x>>6) uniform -> weight loads become vmem
    // (round-3 lesson: SGPR 112->48, VALUBusy 34->11%, 3x stall).
    int c0 = __builtin_amdgcn_readfirstlane(wv * 16);

    int p = blockIdx.x * 64 + lane;   // 64 consecutive pixels per block
    int j = p & (W_ - 1);
    int i = (p >> 7) & (H_ - 1);
    int n = p >> 14;
    int pix = i * W_ + j;

    float a[18];
    #pragma unroll
    for (int o = 0; o < 18; ++o) a[o] = 0.f;

    const float* xb = x + (size_t)n * C_ * HW_ + (size_t)c0 * HW_;
    for (int cc = 0; cc < 16; ++cc) {
        int c = c0 + cc;              // SGPR + loop var -> uniform -> s_load
        const float* s = xb + cc * HW_;
        float xc = s[pix];
        float xl = (j > 0)      ? s[pix - 1]  : 0.f;
        float xr = (j < W_ - 1) ? s[pix + 1]  : 0.f;
        float xu = (i > 0)      ? s[pix - W_] : 0.f;
        float xd = (i < H_ - 1) ? s[pix + W_] : 0.f;
        const float* wh = w_off_h  + c * 3;
        const float* wm = w_mask_h + c * 3;
        const float* wn = w_off_v  + c * 3;
        const float* wq = w_mask_v + c * 3;
        #pragma unroll
        for (int o = 0; o < 6; ++o) {
            a[o]   = fmaf(xl, wh[o*192+0], fmaf(xc, wh[o*192+1], fmaf(xr, wh[o*192+2], a[o])));
            a[9+o] = fmaf(xu, wn[o*192+0], fmaf(xc, wn[o*192+1], fmaf(xd, wn[o*192+2], a[9+o])));
        }
        #pragma unroll
        for (int o = 0; o < 3; ++o) {
            a[6+o]  = fmaf(xl, wm[o*192+0], fmaf(xc, wm[o*192+1], fmaf(xr, wm[o*192+2], a[6+o])));
            a[15+o] = fmaf(xu, wq[o*192+0], fmaf(xc, wq[o*192+1], fmaf(xd, wq[o*192+2], a[15+o])));
        }
    }

    // Cross-wave reduction: [slice][idx][px], px=lane consecutive -> no conflicts
    __shared__ float red[4][18][64];
    #pragma unroll
    for (int o = 0; o < 18; ++o) red[wv][o][lane] = a[o];
    __syncthreads();

    for (int v = threadIdx.x; v < 18 * 64; v += 256) {
        int idx = v >> 6;
        int px  = v & 63;
        float sum = red[0][idx][px] + red[1][idx][px]
                  + red[2][idx][px] + red[3][idx][px];
        int pg  = blockIdx.x * 64 + px;
        int nn  = pg >> 14;
        int pixg = pg & (HW_ - 1);
        if (idx < 6) {
            sum += b_off_h[idx];
            off_h[((size_t)nn * 6 + idx) * HW_ + pixg] = sum;
        } else if (idx < 9) {
            sum += b_mask_h[idx - 6];
            mask_h[((size_t)nn * 3 + (idx - 6)) * HW_ + pixg] = 1.f / (1.f + __expf(-sum));
        } else if (idx < 15) {
            sum += b_off_v[idx - 9];
            off_v[((size_t)nn * 6 + (idx - 9)) * HW_ + pixg] = sum;
        } else {
            sum += b_mask_v[idx - 15];
            mask_v[((size_t)nn * 3 + (idx - 15)) * HW_ + pixg] = 1.f / (1.f + __expf(-sum));
        }
    }
}

// ---------------------------------------------------------------------------
// Kernel B/C: deformable axial conv pass.
// Block = 256 threads = 4 waves x 64 pixels. Wave w accumulates input
// channels [16w,16w+16) into 64 output partials. c0 via readfirstlane so
// weight reads are s_load (SGPR-prefetched). acc[] only ever sees
// compile-time indices (round-2 lesson: runtime index -> scratch demotion).
// Partials reduced across the 4 waves via 16KB LDS, fully unrolled.
// ---------------------------------------------------------------------------
__global__ __launch_bounds__(256) void deform_kernel(
    const float* __restrict__ src, const float* __restrict__ off,
    const float* __restrict__ mask, const float* __restrict__ wT,
    const float* __restrict__ bias, float* __restrict__ out, int axis)
{
    int lane = threadIdx.x & 63;
    int wv   = threadIdx.x >> 6;      // channel slice 0..3
    int c0 = __builtin_amdgcn_readfirstlane(wv * 16);   // SGPR slice base

    int p = blockIdx.x * 64 + lane;
    int j = p & (W_ - 1);
    int i = (p >> 7) & (H_ - 1);
    int n = p >> 14;
    int pix = i * W_ + j;

    int a00[3], a01[3], a10[3], a11[3];
    float w00[3], w01[3], w10[3], w11[3];

    #pragma unroll
    for (int k = 0; k < 3; ++k) {
        float dy = off[(((size_t)n * 3 + k) * 2 + 0) * HW_ + pix];
        float dx = off[(((size_t)n * 3 + k) * 2 + 1) * HW_ + pix];
        float m  = mask[((size_t)n * 3 + k) * HW_ + pix];
        float py = (float)i + dy + (axis ? (float)(k - 1) : 0.f);
        float px = (float)j + dx + (axis ? 0.f : (float)(k - 1));
        float y0f = floorf(py), x0f = floorf(px);
        float wy = py - y0f, wx = px - x0f;
        int y0 = (int)y0f, x0 = (int)x0f;
        int y1 = y0 + 1, x1 = x0 + 1;
        bool vy0 = (y0 >= 0) && (y0 < H_);
        bool vy1 = (y1 >= 0) && (y1 < H_);
        bool vx0 = (x0 >= 0) && (x0 < W_);
        bool vx1 = (x1 >= 0) && (x1 < W_);
        int y0c = min(max(y0, 0), H_ - 1), y1c = min(max(y1, 0), H_ - 1);
        int x0c = min(max(x0, 0), W_ - 1), x1c = min(max(x1, 0), W_ - 1);
        a00[k] = y0c * W_ + x0c;  a01[k] = y0c * W_ + x1c;
        a10[k] = y1c * W_ + x0c;  a11[k] = y1c * W_ + x1c;
        float wy1 = 1.f - wy, wx1 = 1.f - wx;
        w00[k] = (vy0 && vx0) ? wy1 * wx1 * m : 0.f;
        w01[k] = (vy0 && vx1) ? wy1 * wx  * m : 0.f;
        w10[k] = (vy1 && vx0) ? wy  * wx1 * m : 0.f;
        w11[k] = (vy1 && vx1) ? wy  * wx  * m : 0.f;
    }

    float acc[64];
    #pragma unroll
    for (int o = 0; o < 64; ++o) acc[o] = 0.f;

    const float* sb = src + (size_t)n * C_ * HW_ + (size_t)c0 * HW_;
    const float* wp = wT + c0 * 192;
    for (int cc = 0; cc < 16; ++cc) {
        const float* s = sb + cc * HW_;
        float vk[3];
        #pragma unroll
        for (int k = 0; k < 3; ++k) {
            vk[k] = fmaf(w00[k], s[a00[k]],
                    fmaf(w01[k], s[a01[k]],
                    fmaf(w10[k], s[a10[k]],
                         w11[k] * s[a11[k]])));
        }
        const float* wr = wp + cc * 192;   // uniform -> s_load
        #pragma unroll
        for (int o = 0; o < 64; ++o) {
            acc[o] = fmaf(vk[0], wr[o],
                     fmaf(vk[1], wr[64 + o],
                     fmaf(vk[2], wr[128 + o], acc[o])));
        }
    }

    // Cross-wave reduction in 4 chunks of 16 outputs (16 KB LDS).
    __shared__ float red[4][16][64];
    int pg = blockIdx.x * 64;
    int nn = pg >> 14;
    int pixg0 = pg & (HW_ - 1);

#define REDUCE_CHUNK(Q)                                                     \
    {                                                                       \
        if ((Q) > 0) __syncthreads();                                       \
        _Pragma("unroll")                                                   \
        for (int o = 0; o < 16; ++o) red[wv][o][lane] = acc[(Q) * 16 + o];  \
        __syncthreads();                                                    \
        _Pragma("unroll")                                                   \
        for (int k = 0; k < 4; ++k) {                                       \
            int v = threadIdx.x + k * 256;                                  \
            int o = v >> 6;                                                 \
            int px = v & 63;                                                \
            float sum = red[0][o][px] + red[1][o][px]                       \
                      + red[2][o][px] + red[3][o][px];                      \
            int oo = (Q) * 16 + o;                                          \
            out[((size_t)nn * C_ + oo) * HW_ + pixg0 + px] = sum + bias[oo];\
        }                                                                   \
    }

    REDUCE_CHUNK(0)
    REDUCE_CHUNK(1)
    REDUCE_CHUNK(2)
    REDUCE_CHUNK(3)
#undef REDUCE_CHUNK
}

// ---------------------------------------------------------------------------
extern "C" void kernel_launch(void* const* d_in, const int* in_sizes, int n_in,
                              void* d_out, int out_size, void* d_ws, size_t ws_size,
                              hipStream_t stream)
{
    const float* x        = (const float*)d_in[0];
    const float* w_off_h  = (const float*)d_in[1];
    const float* b_off_h  = (const float*)d_in[2];
    const float* w_mask_h = (const float*)d_in[3];
    const float* b_mask_h = (const float*)d_in[4];
    const float* w_off_v  = (const float*)d_in[5];
    const float* b_off_v  = (const float*)d_in[6];
    const float* w_mask_v = (const float*)d_in[7];
    const float* b_mask_v = (const float*)d_in[8];
    const float* w_h      = (const float*)d_in[9];
    const float* b_h      = (const float*)d_in[10];
    const float* w_v      = (const float*)d_in[11];
    const float* b_v      = (const float*)d_in[12];

    float* ws     = (float*)d_ws;
    float* off_h  = ws;                   // 786432
    float* mask_h = off_h  + 786432;      // 393216
    float* off_v  = mask_h + 393216;      // 786432
    float* mask_v = off_v  + 786432;      // 393216
    float* x_h    = mask_v + 393216;      // 8388608
    float* wT_h   = x_h    + 8388608;     // 12288
    float* wT_v   = wT_h   + 12288;       // 12288

    dim3 grid(NPIX / 64), block(256);     // 4 waves per 64-pixel group
    offs_kernel<<<grid, block, 0, stream>>>(x,
        w_off_h, b_off_h, w_mask_h, b_mask_h,
        w_off_v, b_off_v, w_mask_v, b_mask_v,
        w_h, w_v,
        off_h, mask_h, off_v, mask_v, wT_h, wT_v);

    deform_kernel<<<grid, block, 0, stream>>>(x,   off_h, mask_h, wT_h, b_h, x_h,          0);
    deform_kernel<<<grid, block, 0, stream>>>(x_h, off_v, mask_v, wT_v, b_v, (float*)d_out, 1);
}

// Round 5
// 268.850 us; speedup vs baseline: 2.8776x; 1.0613x over previous
//
#include <hip/hip_runtime.h>

#define C_ 64
#define H_ 128
#define W_ 128
#define B_ 8
#define HW_ (H_*W_)
#define NPIX (B_*HW_)

typedef _Float16 half8 __attribute__((ext_vector_type(8)));
typedef float floatx4 __attribute__((ext_vector_type(4)));

// ---------------------------------------------------------------------------
// Prep: pack offset/mask weights into contiguous per-channel rows
// wOffAll[c][56] (so offs_kernel's weight reads become wide s_loads), and
// cast the deform conv weights to f16 (A-operand layout [o][ck] = original
// flat layout of w_h/w_v). Separate launch: offs_kernel consumes wOffAll.
// ---------------------------------------------------------------------------
__global__ __launch_bounds__(256) void prep_kernel(
    const float* __restrict__ w_off_h, const float* __restrict__ w_mask_h,
    const float* __restrict__ w_off_v, const float* __restrict__ w_mask_v,
    const float* __restrict__ w_h, const float* __restrict__ w_v,
    float* __restrict__ wOffAll, _Float16* __restrict__ wF16_h,
    _Float16* __restrict__ wF16_v)
{
    int gid = blockIdx.x * 256 + threadIdx.x;
    if (gid < 64 * 56) {
        int c = gid / 56, idx = gid - 56 * c;
        float v = 0.f;
        if (idx < 18)      v = w_off_h [((idx      ) / 3) * 192 + c * 3 + (idx      ) % 3];
        else if (idx < 27) v = w_mask_h[((idx - 18) / 3) * 192 + c * 3 + (idx - 18) % 3];
        else if (idx < 45) v = w_off_v [((idx - 27) / 3) * 192 + c * 3 + (idx - 27) % 3];
        else if (idx < 54) v = w_mask_v[((idx - 45) / 3) * 192 + c * 3 + (idx - 45) % 3];
        wOffAll[c * 56 + idx] = v;
    } else if (gid < 3584 + 12288) {
        int i = gid - 3584;
        wF16_h[i] = (_Float16)w_h[i];
    } else if (gid < 3584 + 24576) {
        int i = gid - 3584 - 12288;
        wF16_v[i] = (_Float16)w_v[i];
    }
}

// ---------------------------------------------------------------------------
// Offset/mask convs. Block = 4 waves x 64 px; wave w handles channels
// [16w,16w+16). Weights from wOffAll[c][56]: contiguous + wave-uniform ->
// wide s_load_dwordx16 instead of 54 scattered s_load_dword (round-4 offs
// was ~87us on scattered scalar loads).
// ---------------------------------------------------------------------------
__global__ __launch_bounds__(256) void offs_kernel(
    const float* __restrict__ x, const float* __restrict__ wOffAll,
    const float* __restrict__ b_off_h, const float* __restrict__ b_mask_h,
    const float* __restrict__ b_off_v, const float* __restrict__ b_mask_v,
    float* __restrict__ off_h, float* __restrict__ mask_h,
    float* __restrict__ off_v, float* __restrict__ mask_v)
{
    int lane = threadIdx.x & 63;
    int wv   = threadIdx.x >> 6;
    int c0 = __builtin_amdgcn_readfirstlane(wv << 4);   // SGPR slice base

    int p = blockIdx.x * 64 + lane;
    int j = p & (W_ - 1);
    int i = (p >> 7) & (H_ - 1);
    int n = p >> 14;
    int pix = i * W_ + j;

    float a[18];
    #pragma unroll
    for (int o = 0; o < 18; ++o) a[o] = 0.f;

    const float* xb = x + (size_t)n * C_ * HW_ + (size_t)c0 * HW_;
    for (int cc = 0; cc < 16; ++cc) {
        const float* s = xb + cc * HW_;
        float xc = s[pix];
        float xl = (j > 0)      ? s[pix - 1]  : 0.f;
        float xr = (j < W_ - 1) ? s[pix + 1]  : 0.f;
        float xu = (i > 0)      ? s[pix - W_] : 0.f;
        float xd = (i < H_ - 1) ? s[pix + W_] : 0.f;
        const float* wc = wOffAll + (c0 + cc) * 56;   // uniform, contiguous
        #pragma unroll
        for (int o = 0; o < 6; ++o) {
            a[o]   = fmaf(xl, wc[3*o],    fmaf(xc, wc[3*o+1],    fmaf(xr, wc[3*o+2],    a[o])));
            a[9+o] = fmaf(xu, wc[27+3*o], fmaf(xc, wc[27+3*o+1], fmaf(xd, wc[27+3*o+2], a[9+o])));
        }
        #pragma unroll
        for (int o = 0; o < 3; ++o) {
            a[6+o]  = fmaf(xl, wc[18+3*o], fmaf(xc, wc[18+3*o+1], fmaf(xr, wc[18+3*o+2], a[6+o])));
            a[15+o] = fmaf(xu, wc[45+3*o], fmaf(xc, wc[45+3*o+1], fmaf(xd, wc[45+3*o+2], a[15+o])));
        }
    }

    __shared__ float red[4][18][64];
    #pragma unroll
    for (int o = 0; o < 18; ++o) red[wv][o][lane] = a[o];
    __syncthreads();

    for (int v = threadIdx.x; v < 18 * 64; v += 256) {
        int idx = v >> 6;
        int px  = v & 63;
        float sum = red[0][idx][px] + red[1][idx][px]
                  + red[2][idx][px] + red[3][idx][px];
        int pg  = blockIdx.x * 64 + px;
        int nn  = pg >> 14;
        int pixg = pg & (HW_ - 1);
        if (idx < 6) {
            sum += b_off_h[idx];
            off_h[((size_t)nn * 6 + idx) * HW_ + pixg] = sum;
        } else if (idx < 9) {
            sum += b_mask_h[idx - 6];
            mask_h[((size_t)nn * 3 + (idx - 6)) * HW_ + pixg] = 1.f / (1.f + __expf(-sum));
        } else if (idx < 15) {
            sum += b_off_v[idx - 9];
            off_v[((size_t)nn * 6 + (idx - 9)) * HW_ + pixg] = sum;
        } else {
            sum += b_mask_v[idx - 15];
            mask_v[((size_t)nn * 3 + (idx - 15)) * HW_ + pixg] = 1.f / (1.f + __expf(-sum));
        }
    }
}

// ---------------------------------------------------------------------------
// Deformable axial conv pass, MFMA version.
// Block = 4 waves x 64 px. Phase 1: wave w samples channels [16w,16w+16)
// (12 gathers + bilinear blend per (c,px), fp32) and stores val[ck][px] as
// f16 into LDS valT[px][200] (400-B rows: quad-stagger -> conflict-optimal
// for b128 writes/reads). Phase 2: wave w computes outputs [16w,16w+16) x
// 64 px via mfma_f32_16x16x32_f16; A-frags (weights) loaded ONCE per wave
// (24 VGPRs) -- replaces round-4's 12KB/wave scalar weight re-reads.
// f16 error ~3e-3 total vs threshold 2.17e-2.
// ---------------------------------------------------------------------------
__global__ __launch_bounds__(256, 4) void deform_kernel(
    const float* __restrict__ src, const float* __restrict__ off,
    const float* __restrict__ mask, const _Float16* __restrict__ wF16,
    const float* __restrict__ bias, float* __restrict__ out, int axis)
{
    __shared__ __align__(16) _Float16 valT[64][200];

    int lane = threadIdx.x & 63;
    int wv   = threadIdx.x >> 6;
    int c0 = __builtin_amdgcn_readfirstlane(wv << 4);   // channel/output slice

    int p = blockIdx.x * 64 + lane;
    int j = p & (W_ - 1);
    int i = (p >> 7) & (H_ - 1);
    int n = p >> 14;
    int pix = i * W_ + j;

    // ---- per-pixel tap setup (fp32) ----
    int a00[3], a01[3], a10[3], a11[3];
    float w00[3], w01[3], w10[3], w11[3];
    #pragma unroll
    for (int k = 0; k < 3; ++k) {
        float dy = off[(((size_t)n * 3 + k) * 2 + 0) * HW_ + pix];
        float dx = off[(((size_t)n * 3 + k) * 2 + 1) * HW_ + pix];
        float m  = mask[((size_t)n * 3 + k) * HW_ + pix];
        float py = (float)i + dy + (axis ? (float)(k - 1) : 0.f);
        float px = (float)j + dx + (axis ? 0.f : (float)(k - 1));
        float y0f = floorf(py), x0f = floorf(px);
        float wy = py - y0f, wx = px - x0f;
        int y0 = (int)y0f, x0 = (int)x0f;
        int y1 = y0 + 1, x1 = x0 + 1;
        bool vy0 = (y0 >= 0) && (y0 < H_);
        bool vy1 = (y1 >= 0) && (y1 < H_);
        bool vx0 = (x0 >= 0) && (x0 < W_);
        bool vx1 = (x1 >= 0) && (x1 < W_);
        int y0c = min(max(y0, 0), H_ - 1), y1c = min(max(y1, 0), H_ - 1);
        int x0c = min(max(x0, 0), W_ - 1), x1c = min(max(x1, 0), W_ - 1);
        a00[k] = y0c * W_ + x0c;  a01[k] = y0c * W_ + x1c;
        a10[k] = y1c * W_ + x0c;  a11[k] = y1c * W_ + x1c;
        float wy1 = 1.f - wy, wx1 = 1.f - wx;
        w00[k] = (vy0 && vx0) ? wy1 * wx1 * m : 0.f;
        w01[k] = (vy0 && vx1) ? wy1 * wx  * m : 0.f;
        w10[k] = (vy1 && vx0) ? wy  * wx1 * m : 0.f;
        w11[k] = (vy1 && vx1) ? wy  * wx  * m : 0.f;
    }

    // ---- phase 1: sample 16 channels x 3 taps -> f16 -> LDS ----
    const float* sb = src + (size_t)n * C_ * HW_ + (size_t)c0 * HW_;
    #pragma unroll
    for (int g = 0; g < 2; ++g) {
        half8 t8[3];
        #pragma unroll
        for (int cl = 0; cl < 8; ++cl) {
            const float* s = sb + (g * 8 + cl) * HW_;
            #pragma unroll
            for (int k = 0; k < 3; ++k) {
                float v = fmaf(w00[k], s[a00[k]],
                          fmaf(w01[k], s[a01[k]],
                          fmaf(w10[k], s[a10[k]],
                               w11[k] * s[a11[k]])));
                t8[(cl * 3 + k) >> 3][(cl * 3 + k) & 7] = (_Float16)v;
            }
        }
        #pragma unroll
        for (int w = 0; w < 3; ++w)
            *((half8*)&valT[lane][wv * 48 + g * 24 + w * 8]) = t8[w];
    }
    __syncthreads();

    // ---- phase 2: MFMA contraction, wave wv -> outputs [c0, c0+16) ----
    const _Float16* wpA = wF16 + (size_t)(c0 + (lane & 15)) * 192 + ((lane >> 4) << 3);
    half8 A0 = *((const half8*)(wpA +   0));
    half8 A1 = *((const half8*)(wpA +  32));
    half8 A2 = *((const half8*)(wpA +  64));
    half8 A3 = *((const half8*)(wpA +  96));
    half8 A4 = *((const half8*)(wpA + 128));
    half8 A5 = *((const half8*)(wpA + 160));

    int col  = lane & 15;
    int orow = c0 + ((lane >> 4) << 2);
    floatx4 bv = *((const floatx4*)&bias[orow]);
    float* ob = out + ((size_t)n * C_ + orow) * HW_
                    + ((blockIdx.x * 64) & (HW_ - 1)) + col;

#define TILE(T)                                                               \
    {                                                                         \
        const _Float16* bp = &valT[(T) * 16 + col][(lane >> 4) << 3];         \
        floatx4 acc = {0.f, 0.f, 0.f, 0.f};                                   \
        acc = __builtin_amdgcn_mfma_f32_16x16x32_f16(A0, *((const half8*)(bp +   0)), acc, 0, 0, 0); \
        acc = __builtin_amdgcn_mfma_f32_16x16x32_f16(A1, *((const half8*)(bp +  32)), acc, 0, 0, 0); \
        acc = __builtin_amdgcn_mfma_f32_16x16x32_f16(A2, *((const half8*)(bp +  64)), acc, 0, 0, 0); \
        acc = __builtin_amdgcn_mfma_f32_16x16x32_f16(A3, *((const half8*)(bp +  96)), acc, 0, 0, 0); \
        acc = __builtin_amdgcn_mfma_f32_16x16x32_f16(A4, *((const half8*)(bp + 128)), acc, 0, 0, 0); \
        acc = __builtin_amdgcn_mfma_f32_16x16x32_f16(A5, *((const half8*)(bp + 160)), acc, 0, 0, 0); \
        ob[(T) * 16 + (size_t)0 * HW_] = acc[0] + bv[0];                      \
        ob[(T) * 16 + (size_t)1 * HW_] = acc[1] + bv[1];                      \
        ob[(T) * 16 + (size_t)2 * HW_] = acc[2] + bv[2];                      \
        ob[(T) * 16 + (size_t)3 * HW_] = acc[3] + bv[3];                      \
    }

    TILE(0)
    TILE(1)
    TILE(2)
    TILE(3)
#undef TILE
}

// ---------------------------------------------------------------------------
extern "C" void kernel_launch(void* const* d_in, const int* in_sizes, int n_in,
                              void* d_out, int out_size, void* d_ws, size_t ws_size,
                              hipStream_t stream)
{
    const float* x        = (const float*)d_in[0];
    const float* w_off_h  = (const float*)d_in[1];
    const float* b_off_h  = (const float*)d_in[2];
    const float* w_mask_h = (const float*)d_in[3];
    const float* b_mask_h = (const float*)d_in[4];
    const float* w_off_v  = (const float*)d_in[5];
    const float* b_off_v  = (const float*)d_in[6];
    const float* w_mask_v = (const float*)d_in[7];
    const float* b_mask_v = (const float*)d_in[8];
    const float* w_h      = (const float*)d_in[9];
    const float* b_h      = (const float*)d_in[10];
    const float* w_v      = (const float*)d_in[11];
    const float* b_v      = (const float*)d_in[12];

    float* ws      = (float*)d_ws;
    float* off_h   = ws;                    // 786432
    float* mask_h  = off_h  + 786432;       // 393216
    float* off_v   = mask_h + 393216;       // 786432
    float* mask_v  = off_v  + 786432;       // 393216
    float* x_h     = mask_v + 393216;       // 8388608
    float* wOffAll = x_h    + 8388608;      // 3584
    _Float16* wF16_h = (_Float16*)(wOffAll + 3584);  // 12288 halfs (16B-aligned)
    _Float16* wF16_v = wF16_h + 12288;               // 12288 halfs

    prep_kernel<<<110, 256, 0, stream>>>(
        w_off_h, w_mask_h, w_off_v, w_mask_v, w_h, w_v,
        wOffAll, wF16_h, wF16_v);

    dim3 grid(NPIX / 64), block(256);
    offs_kernel<<<grid, block, 0, stream>>>(x, wOffAll,
        b_off_h, b_mask_h, b_off_v, b_mask_v,
        off_h, mask_h, off_v, mask_v);

    deform_kernel<<<grid, block, 0, stream>>>(x,   off_h, mask_h, wF16_h, b_h, x_h,           0);
    deform_kernel<<<grid, block, 0, stream>>>(x_h, off_v, mask_v, wF16_v, b_v, (float*)d_out, 1);
}

// Round 6
// 228.974 us; speedup vs baseline: 3.3787x; 1.1742x over previous
//
#include <hip/hip_runtime.h>

#define C_ 64
#define H_ 128
#define W_ 128
#define B_ 8
#define HW_ (H_*W_)
#define NPIX (B_*HW_)

typedef _Float16 half8 __attribute__((ext_vector_type(8)));
typedef float floatx4 __attribute__((ext_vector_type(4)));
// 4-B-aligned pair for bilinear corner loads (x0,x0+1 adjacent in memory).
struct f2 { float x, y; };

// ---------------------------------------------------------------------------
// Prep: pack offset/mask weights into contiguous per-channel rows
// wOffAll[c][56] (wide wave-uniform s_loads) and cast deform weights to f16.
// ---------------------------------------------------------------------------
__global__ __launch_bounds__(256) void prep_kernel(
    const float* __restrict__ w_off_h, const float* __restrict__ w_mask_h,
    const float* __restrict__ w_off_v, const float* __restrict__ w_mask_v,
    const float* __restrict__ w_h, const float* __restrict__ w_v,
    float* __restrict__ wOffAll, _Float16* __restrict__ wF16_h,
    _Float16* __restrict__ wF16_v)
{
    int gid = blockIdx.x * 256 + threadIdx.x;
    if (gid < 64 * 56) {
        int c = gid / 56, idx = gid - 56 * c;
        float v = 0.f;
        if (idx < 18)      v = w_off_h [((idx      ) / 3) * 192 + c * 3 + (idx      ) % 3];
        else if (idx < 27) v = w_mask_h[((idx - 18) / 3) * 192 + c * 3 + (idx - 18) % 3];
        else if (idx < 45) v = w_off_v [((idx - 27) / 3) * 192 + c * 3 + (idx - 27) % 3];
        else if (idx < 54) v = w_mask_v[((idx - 45) / 3) * 192 + c * 3 + (idx - 45) % 3];
        wOffAll[c * 56 + idx] = v;
    } else if (gid < 3584 + 12288) {
        int i = gid - 3584;
        wF16_h[i] = (_Float16)w_h[i];
    } else if (gid < 3584 + 24576) {
        int i = gid - 3584 - 12288;
        wF16_v[i] = (_Float16)w_v[i];
    }
}

// ---------------------------------------------------------------------------
// Bilinear tap -> paired-load form. Corners (y,x0),(y,x0+1) fetched as one
// 8-B load at xb=clamp(x0,0,W-2); edge cases folded into pair weights
// (s0/s1 selects, validity -> zero weight), so the per-channel inner loop
// is just 2 pair-loads + 4 FMAs per tap. Halves gather-instruction count
// (round-5 lesson: deform is TA/latency-bound, MfmaUtil 1.5%, VALU 5.5%).
// ---------------------------------------------------------------------------
__device__ __forceinline__ void tap_setup(
    float fi, float fj, float dy, float dx, float m, float kyo, float kxo,
    int& b0, int& b1, float& wA0, float& wB0, float& wA1, float& wB1)
{
    float py = fi + kyo + dy;
    float px = fj + kxo + dx;
    float y0f = floorf(py), x0f = floorf(px);
    float wy = py - y0f, wx = px - x0f;
    int y0 = (int)y0f, x0 = (int)x0f;
    int y1 = y0 + 1, x1 = x0 + 1;
    bool vy0 = (y0 >= 0) && (y0 < H_);
    bool vy1 = (y1 >= 0) && (y1 < H_);
    bool vx0 = (x0 >= 0) && (x0 < W_);
    bool vx1 = (x1 >= 0) && (x1 < W_);
    int y0c = min(max(y0, 0), H_ - 1), y1c = min(max(y1, 0), H_ - 1);
    int xb = min(max(x0, 0), W_ - 2);
    int s0 = min(max(x0 - xb, 0), 1);      // v00 = pair[s0]
    int s1 = min(max(x1 - xb, 0), 1);      // v01 = pair[s1]
    float wy1 = 1.f - wy, wx1 = 1.f - wx;
    float w00 = (vy0 && vx0) ? wy1 * wx1 * m : 0.f;
    float w01 = (vy0 && vx1) ? wy1 * wx  * m : 0.f;
    float w10 = (vy1 && vx0) ? wy  * wx1 * m : 0.f;
    float w11 = (vy1 && vx1) ? wy  * wx  * m : 0.f;
    wA0 = (s0 ? 0.f : w00) + (s1 ? 0.f : w01);
    wB0 = (s0 ? w00 : 0.f) + (s1 ? w01 : 0.f);
    wA1 = (s0 ? 0.f : w10) + (s1 ? 0.f : w11);
    wB1 = (s0 ? w10 : 0.f) + (s1 ? w11 : 0.f);
    b0 = y0c * W_ + xb;
    b1 = y1c * W_ + xb;
}

// ---------------------------------------------------------------------------
// Fused horizontal pass: offs prologue (h+v offsets/masks from x; h kept in
// LDS, v written to ws) + deformable (1,K) conv via MFMA. Removes the
// standalone offs kernel (its stalls now overlap the gather stalls here)
// and the off_h/mask_h HBM round-trip. smem is a union: red[4][18][64]
// (reduce) then valT[64][200] (f16 B-tile).
// ---------------------------------------------------------------------------
__global__ __launch_bounds__(256, 4) void deform_h_kernel(
    const float* __restrict__ x, const float* __restrict__ wOffAll,
    const float* __restrict__ b_off_h, const float* __restrict__ b_mask_h,
    const float* __restrict__ b_off_v, const float* __restrict__ b_mask_v,
    const _Float16* __restrict__ wF16, const float* __restrict__ bias,
    float* __restrict__ off_v, float* __restrict__ mask_v,
    float* __restrict__ out)
{
    __shared__ __align__(16) char smem[25600];
    float (*red)[18][64] = reinterpret_cast<float(*)[18][64]>(smem);
    _Float16 (*valT)[200] = reinterpret_cast<_Float16(*)[200]>(smem);

    int lane = threadIdx.x & 63;
    int wv   = threadIdx.x >> 6;
    int c0 = __builtin_amdgcn_readfirstlane(wv << 4);   // SGPR slice base

    int p = blockIdx.x * 64 + lane;
    int j = p & (W_ - 1);
    int i = (p >> 7) & (H_ - 1);
    int n = p >> 14;
    int pix = i * W_ + j;

    // ---- offs prologue: 5-pt stencil over this wave's 16 channels ----
    float a[18];
    #pragma unroll
    for (int o = 0; o < 18; ++o) a[o] = 0.f;

    const float* xs = x + (size_t)n * C_ * HW_ + (size_t)c0 * HW_;
    for (int cc = 0; cc < 16; ++cc) {
        const float* s = xs + cc * HW_;
        float xc = s[pix];
        float xl = (j > 0)      ? s[pix - 1]  : 0.f;
        float xr = (j < W_ - 1) ? s[pix + 1]  : 0.f;
        float xu = (i > 0)      ? s[pix - W_] : 0.f;
        float xd = (i < H_ - 1) ? s[pix + W_] : 0.f;
        const float* wc = wOffAll + (c0 + cc) * 56;   // uniform -> s_load
        #pragma unroll
        for (int o = 0; o < 6; ++o) {
            a[o]   = fmaf(xl, wc[3*o],    fmaf(xc, wc[3*o+1],    fmaf(xr, wc[3*o+2],    a[o])));
            a[9+o] = fmaf(xu, wc[27+3*o], fmaf(xc, wc[27+3*o+1], fmaf(xd, wc[27+3*o+2], a[9+o])));
        }
        #pragma unroll
        for (int o = 0; o < 3; ++o) {
            a[6+o]  = fmaf(xl, wc[18+3*o], fmaf(xc, wc[18+3*o+1], fmaf(xr, wc[18+3*o+2], a[6+o])));
            a[15+o] = fmaf(xu, wc[45+3*o], fmaf(xc, wc[45+3*o+1], fmaf(xd, wc[45+3*o+2], a[15+o])));
        }
    }

    // ---- cross-wave reduce: h-set -> LDS (consumed below), v-set -> ws ----
    #pragma unroll
    for (int o = 0; o < 18; ++o) red[wv][o][lane] = a[o];
    __syncthreads();

    for (int v = threadIdx.x; v < 18 * 64; v += 256) {
        int idx = v >> 6;
        int px  = v & 63;
        float sum = red[0][idx][px] + red[1][idx][px]
                  + red[2][idx][px] + red[3][idx][px];
        int pg  = blockIdx.x * 64 + px;
        int nn  = pg >> 14;
        int pixg = pg & (HW_ - 1);
        if (idx < 6) {
            red[0][idx][px] = sum + b_off_h[idx];    // (idx,px) has unique owner
        } else if (idx < 9) {
            red[0][idx][px] = 1.f / (1.f + __expf(-(sum + b_mask_h[idx - 6])));
        } else if (idx < 15) {
            off_v[((size_t)nn * 6 + (idx - 9)) * HW_ + pixg] = sum + b_off_v[idx - 9];
        } else {
            mask_v[((size_t)nn * 3 + (idx - 15)) * HW_ + pixg] =
                1.f / (1.f + __expf(-(sum + b_mask_v[idx - 15])));
        }
    }
    __syncthreads();

    float dyk[3], dxk[3], mk[3];
    #pragma unroll
    for (int k = 0; k < 3; ++k) {
        dyk[k] = red[0][2*k    ][lane];
        dxk[k] = red[0][2*k + 1][lane];
        mk [k] = red[0][6 + k  ][lane];
    }
    __syncthreads();   // all reads of red done before valT overwrites smem

    // ---- tap setup (horizontal: kyo=0, kxo=k-1) ----
    int b0[3], b1[3];
    float wA0[3], wB0[3], wA1[3], wB1[3];
    #pragma unroll
    for (int k = 0; k < 3; ++k)
        tap_setup((float)i, (float)j, dyk[k], dxk[k], mk[k], 0.f, (float)(k - 1),
                  b0[k], b1[k], wA0[k], wB0[k], wA1[k], wB1[k]);

    // ---- phase 1: paired gathers -> f16 -> LDS ----
    #pragma unroll
    for (int g = 0; g < 2; ++g) {
        half8 t8[3];
        #pragma unroll
        for (int cl = 0; cl < 8; ++cl) {
            const float* s = xs + (g * 8 + cl) * HW_;
            #pragma unroll
            for (int k = 0; k < 3; ++k) {
                f2 p0 = *(const f2*)(s + b0[k]);
                f2 p1 = *(const f2*)(s + b1[k]);
                float v = fmaf(wA0[k], p0.x, fmaf(wB0[k], p0.y,
                          fmaf(wA1[k], p1.x, wB1[k] * p1.y)));
                int t = cl * 3 + k;
                t8[t >> 3][t & 7] = (_Float16)v;
            }
        }
        #pragma unroll
        for (int w = 0; w < 3; ++w)
            *((half8*)&valT[lane][wv * 48 + g * 24 + w * 8]) = t8[w];
    }
    __syncthreads();

    // ---- phase 2: MFMA contraction (round-5 verified layout) ----
    const _Float16* wpA = wF16 + (size_t)(c0 + (lane & 15)) * 192 + ((lane >> 4) << 3);
    half8 A0 = *((const half8*)(wpA +   0));
    half8 A1 = *((const half8*)(wpA +  32));
    half8 A2 = *((const half8*)(wpA +  64));
    half8 A3 = *((const half8*)(wpA +  96));
    half8 A4 = *((const half8*)(wpA + 128));
    half8 A5 = *((const half8*)(wpA + 160));

    int col  = lane & 15;
    int orow = c0 + ((lane >> 4) << 2);
    floatx4 bv = *((const floatx4*)&bias[orow]);
    float* ob = out + ((size_t)n * C_ + orow) * HW_
                    + ((blockIdx.x * 64) & (HW_ - 1)) + col;

#define TILE(T)                                                               \
    {                                                                         \
        const _Float16* bp = &valT[(T) * 16 + col][(lane >> 4) << 3];         \
        floatx4 acc = {0.f, 0.f, 0.f, 0.f};                                   \
        acc = __builtin_amdgcn_mfma_f32_16x16x32_f16(A0, *((const half8*)(bp +   0)), acc, 0, 0, 0); \
        acc = __builtin_amdgcn_mfma_f32_16x16x32_f16(A1, *((const half8*)(bp +  32)), acc, 0, 0, 0); \
        acc = __builtin_amdgcn_mfma_f32_16x16x32_f16(A2, *((const half8*)(bp +  64)), acc, 0, 0, 0); \
        acc = __builtin_amdgcn_mfma_f32_16x16x32_f16(A3, *((const half8*)(bp +  96)), acc, 0, 0, 0); \
        acc = __builtin_amdgcn_mfma_f32_16x16x32_f16(A4, *((const half8*)(bp + 128)), acc, 0, 0, 0); \
        acc = __builtin_amdgcn_mfma_f32_16x16x32_f16(A5, *((const half8*)(bp + 160)), acc, 0, 0, 0); \
        ob[(T) * 16 + (size_t)0 * HW_] = acc[0] + bv[0];                      \
        ob[(T) * 16 + (size_t)1 * HW_] = acc[1] + bv[1];                      \
        ob[(T) * 16 + (size_t)2 * HW_] = acc[2] + bv[2];                      \
        ob[(T) * 16 + (size_t)3 * HW_] = acc[3] + bv[3];                      \
    }

    TILE(0)
    TILE(1)
    TILE(2)
    TILE(3)
#undef TILE
}

// ---------------------------------------------------------------------------
// Vertical pass: deformable (K,1) conv on x_h; offsets/masks precomputed by
// deform_h_kernel. Same paired-gather phase 1 + MFMA phase 2.
// ---------------------------------------------------------------------------
__global__ __launch_bounds__(256, 4) void deform_v_kernel(
    const float* __restrict__ src, const float* __restrict__ off,
    const float* __restrict__ mask, const _Float16* __restrict__ wF16,
    const float* __restrict__ bias, float* __restrict__ out)
{
    __shared__ __align__(16) _Float16 valT[64][200];

    int lane = threadIdx.x & 63;
    int wv   = threadIdx.x >> 6;
    int c0 = __builtin_amdgcn_readfirstlane(wv << 4);

    int p = blockIdx.x * 64 + lane;
    int j = p & (W_ - 1);
    int i = (p >> 7) & (H_ - 1);
    int n = p >> 14;
    int pix = i * W_ + j;

    int b0[3], b1[3];
    float wA0[3], wB0[3], wA1[3], wB1[3];
    #pragma unroll
    for (int k = 0; k < 3; ++k) {
        float dy = off[(((size_t)n * 3 + k) * 2 + 0) * HW_ + pix];
        float dx = off[(((size_t)n * 3 + k) * 2 + 1) * HW_ + pix];
        float m  = mask[((size_t)n * 3 + k) * HW_ + pix];
        tap_setup((float)i, (float)j, dy, dx, m, (float)(k - 1), 0.f,
                  b0[k], b1[k], wA0[k], wB0[k], wA1[k], wB1[k]);
    }

    const float* sb = src + (size_t)n * C_ * HW_ + (size_t)c0 * HW_;
    #pragma unroll
    for (int g = 0; g < 2; ++g) {
        half8 t8[3];
        #pragma unroll
        for (int cl = 0; cl < 8; ++cl) {
            const float* s = sb + (g * 8 + cl) * HW_;
            #pragma unroll
            for (int k = 0; k < 3; ++k) {
                f2 p0 = *(const f2*)(s + b0[k]);
                f2 p1 = *(const f2*)(s + b1[k]);
                float v = fmaf(wA0[k], p0.x, fmaf(wB0[k], p0.y,
                          fmaf(wA1[k], p1.x, wB1[k] * p1.y)));
                int t = cl * 3 + k;
                t8[t >> 3][t & 7] = (_Float16)v;
            }
        }
        #pragma unroll
        for (int w = 0; w < 3; ++w)
            *((half8*)&valT[lane][wv * 48 + g * 24 + w * 8]) = t8[w];
    }
    __syncthreads();

    const _Float16* wpA = wF16 + (size_t)(c0 + (lane & 15)) * 192 + ((lane >> 4) << 3);
    half8 A0 = *((const half8*)(wpA +   0));
    half8 A1 = *((const half8*)(wpA +  32));
    half8 A2 = *((const half8*)(wpA +  64));
    half8 A3 = *((const half8*)(wpA +  96));
    half8 A4 = *((const half8*)(wpA + 128));
    half8 A5 = *((const half8*)(wpA + 160));

    int col  = lane & 15;
    int orow = c0 + ((lane >> 4) << 2);
    floatx4 bv = *((const floatx4*)&bias[orow]);
    float* ob = out + ((size_t)n * C_ + orow) * HW_
                    + ((blockIdx.x * 64) & (HW_ - 1)) + col;

#define TILE(T)                                                               \
    {                                                                         \
        const _Float16* bp = &valT[(T) * 16 + col][(lane >> 4) << 3];         \
        floatx4 acc = {0.f, 0.f, 0.f, 0.f};                                   \
        acc = __builtin_amdgcn_mfma_f32_16x16x32_f16(A0, *((const half8*)(bp +   0)), acc, 0, 0, 0); \
        acc = __builtin_amdgcn_mfma_f32_16x16x32_f16(A1, *((const half8*)(bp +  32)), acc, 0, 0, 0); \
        acc = __builtin_amdgcn_mfma_f32_16x16x32_f16(A2, *((const half8*)(bp +  64)), acc, 0, 0, 0); \
        acc = __builtin_amdgcn_mfma_f32_16x16x32_f16(A3, *((const half8*)(bp +  96)), acc, 0, 0, 0); \
        acc = __builtin_amdgcn_mfma_f32_16x16x32_f16(A4, *((const half8*)(bp + 128)), acc, 0, 0, 0); \
        acc = __builtin_amdgcn_mfma_f32_16x16x32_f16(A5, *((const half8*)(bp + 160)), acc, 0, 0, 0); \
        ob[(T) * 16 + (size_t)0 * HW_] = acc[0] + bv[0];                      \
        ob[(T) * 16 + (size_t)1 * HW_] = acc[1] + bv[1];                      \
        ob[(T) * 16 + (size_t)2 * HW_] = acc[2] + bv[2];                      \
        ob[(T) * 16 + (size_t)3 * HW_] = acc[3] + bv[3];                      \
    }

    TILE(0)
    TILE(1)
    TILE(2)
    TILE(3)
#undef TILE
}

// ---------------------------------------------------------------------------
extern "C" void kernel_launch(void* const* d_in, const int* in_sizes, int n_in,
                              void* d_out, int out_size, void* d_ws, size_t ws_size,
                              hipStream_t stream)
{
    const float* x        = (const float*)d_in[0];
    const float* w_off_h  = (const float*)d_in[1];
    const float* b_off_h  = (const float*)d_in[2];
    const float* w_mask_h = (const float*)d_in[3];
    const float* b_mask_h = (const float*)d_in[4];
    const float* w_off_v  = (const float*)d_in[5];
    const float* b_off_v  = (const float*)d_in[6];
    const float* w_mask_v = (const float*)d_in[7];
    const float* b_mask_v = (const float*)d_in[8];
    const float* w_h      = (const float*)d_in[9];
    const float* b_h      = (const float*)d_in[10];
    const float* w_v      = (const float*)d_in[11];
    const float* b_v      = (const float*)d_in[12];

    float* ws      = (float*)d_ws;
    float* off_v   = ws;                    // 786432
    float* mask_v  = off_v  + 786432;       // 393216
    float* x_h     = mask_v + 393216;       // 8388608
    float* wOffAll = x_h    + 8388608;      // 3584
    _Float16* wF16_h = (_Float16*)(wOffAll + 3584);  // 12288 halfs
    _Float16* wF16_v = wF16_h + 12288;               // 12288 halfs

    prep_kernel<<<110, 256, 0, stream>>>(
        w_off_h, w_mask_h, w_off_v, w_mask_v, w_h, w_v,
        wOffAll, wF16_h, wF16_v);

    dim3 grid(NPIX / 64), block(256);
    deform_h_kernel<<<grid, block, 0, stream>>>(
        x, wOffAll, b_off_h, b_mask_h, b_off_v, b_mask_v,
        wF16_h, b_h, off_v, mask_v, x_h);

    deform_v_kernel<<<grid, block, 0, stream>>>(
        x_h, off_v, mask_v, wF16_v, b_v, (float*)d_out);
}

// Round 7
// 222.929 us; speedup vs baseline: 3.4703x; 1.0271x over previous
//
#include <hip/hip_runtime.h>

#define C_ 64
#define H_ 128
#define W_ 128
#define B_ 8
#define HW_ (H_*W_)
#define NPIX (B_*HW_)

typedef _Float16 half8 __attribute__((ext_vector_type(8)));
typedef float floatx4 __attribute__((ext_vector_type(4)));
// 4-B-aligned pair for bilinear corner loads (x0,x0+1 adjacent in memory).
struct f2 { float x, y; };

// ---------------------------------------------------------------------------
// Prep: pack offset/mask weights into contiguous per-channel rows
// wOffAll[c][56] (wide wave-uniform s_loads) and cast deform weights to f16.
// ---------------------------------------------------------------------------
__global__ __launch_bounds__(256) void prep_kernel(
    const float* __restrict__ w_off_h, const float* __restrict__ w_mask_h,
    const float* __restrict__ w_off_v, const float* __restrict__ w_mask_v,
    const float* __restrict__ w_h, const float* __restrict__ w_v,
    float* __restrict__ wOffAll, _Float16* __restrict__ wF16_h,
    _Float16* __restrict__ wF16_v)
{
    int gid = blockIdx.x * 256 + threadIdx.x;
    if (gid < 64 * 56) {
        int c = gid / 56, idx = gid - 56 * c;
        float v = 0.f;
        if (idx < 18)      v = w_off_h [((idx      ) / 3) * 192 + c * 3 + (idx      ) % 3];
        else if (idx < 27) v = w_mask_h[((idx - 18) / 3) * 192 + c * 3 + (idx - 18) % 3];
        else if (idx < 45) v = w_off_v [((idx - 27) / 3) * 192 + c * 3 + (idx - 27) % 3];
        else if (idx < 54) v = w_mask_v[((idx - 45) / 3) * 192 + c * 3 + (idx - 45) % 3];
        wOffAll[c * 56 + idx] = v;
    } else if (gid < 3584 + 12288) {
        int i = gid - 3584;
        wF16_h[i] = (_Float16)w_h[i];
    } else if (gid < 3584 + 24576) {
        int i = gid - 3584 - 12288;
        wF16_v[i] = (_Float16)w_v[i];
    }
}

// ---------------------------------------------------------------------------
// Bilinear tap -> paired-load form (round-6 verified). 2 pair-loads + 4 FMAs
// per (channel, tap); edge validity folded into pair weights.
// ---------------------------------------------------------------------------
__device__ __forceinline__ void tap_setup(
    float fi, float fj, float dy, float dx, float m, float kyo, float kxo,
    int& b0, int& b1, float& wA0, float& wB0, float& wA1, float& wB1)
{
    float py = fi + kyo + dy;
    float px = fj + kxo + dx;
    float y0f = floorf(py), x0f = floorf(px);
    float wy = py - y0f, wx = px - x0f;
    int y0 = (int)y0f, x0 = (int)x0f;
    int y1 = y0 + 1, x1 = x0 + 1;
    bool vy0 = (y0 >= 0) && (y0 < H_);
    bool vy1 = (y1 >= 0) && (y1 < H_);
    bool vx0 = (x0 >= 0) && (x0 < W_);
    bool vx1 = (x1 >= 0) && (x1 < W_);
    int y0c = min(max(y0, 0), H_ - 1), y1c = min(max(y1, 0), H_ - 1);
    int xb = min(max(x0, 0), W_ - 2);
    int s0 = min(max(x0 - xb, 0), 1);      // v00 = pair[s0]
    int s1 = min(max(x1 - xb, 0), 1);      // v01 = pair[s1]
    float wy1 = 1.f - wy, wx1 = 1.f - wx;
    float w00 = (vy0 && vx0) ? wy1 * wx1 * m : 0.f;
    float w01 = (vy0 && vx1) ? wy1 * wx  * m : 0.f;
    float w10 = (vy1 && vx0) ? wy  * wx1 * m : 0.f;
    float w11 = (vy1 && vx1) ? wy  * wx  * m : 0.f;
    wA0 = (s0 ? 0.f : w00) + (s1 ? 0.f : w01);
    wB0 = (s0 ? w00 : 0.f) + (s1 ? w01 : 0.f);
    wA1 = (s0 ? 0.f : w10) + (s1 ? 0.f : w11);
    wB1 = (s0 ? w10 : 0.f) + (s1 ? w11 : 0.f);
    b0 = y0c * W_ + xb;
    b1 = y1c * W_ + xb;
}

// XCD-aware swizzle: one image (n) = 4 MB = exactly one XCD's L2. Blocks go
// to XCDs round-robin by blockIdx%8, so n = bid&7 pins image k to XCD k and
// kills the 4.3x cross-XCD HBM re-fetch (round-6: FETCH 144 MB vs 33.5 MB
// unique; gathers miss to HBM at ~900 cyc instead of L2-hit ~200 cyc).
#define SWIZZLE_NP()                        \
    int bid = blockIdx.x;                   \
    int n   = bid & 7;                      \
    int m   = bid >> 3;      /* 0..255 in-image tile */ \
    int pix = m * 64 + lane;                \
    int j = pix & (W_ - 1);                 \
    int i = pix >> 7;

// ---------------------------------------------------------------------------
// Fused horizontal pass: offs prologue (h offsets kept in LDS, v written to
// ws) + deformable (1,K) conv via MFMA.
// ---------------------------------------------------------------------------
__global__ __launch_bounds__(256, 4) void deform_h_kernel(
    const float* __restrict__ x, const float* __restrict__ wOffAll,
    const float* __restrict__ b_off_h, const float* __restrict__ b_mask_h,
    const float* __restrict__ b_off_v, const float* __restrict__ b_mask_v,
    const _Float16* __restrict__ wF16, const float* __restrict__ bias,
    float* __restrict__ off_v, float* __restrict__ mask_v,
    float* __restrict__ out)
{
    __shared__ __align__(16) char smem[25600];
    float (*red)[18][64] = reinterpret_cast<float(*)[18][64]>(smem);
    _Float16 (*valT)[200] = reinterpret_cast<_Float16(*)[200]>(smem);

    int lane = threadIdx.x & 63;
    int wv   = threadIdx.x >> 6;
    int c0 = __builtin_amdgcn_readfirstlane(wv << 4);   // SGPR slice base

    SWIZZLE_NP();

    // ---- offs prologue: 5-pt stencil over this wave's 16 channels ----
    float a[18];
    #pragma unroll
    for (int o = 0; o < 18; ++o) a[o] = 0.f;

    const float* xs = x + (size_t)n * C_ * HW_ + (size_t)c0 * HW_;
    for (int cc = 0; cc < 16; ++cc) {
        const float* s = xs + cc * HW_;
        float xc = s[pix];
        float xl = (j > 0)      ? s[pix - 1]  : 0.f;
        float xr = (j < W_ - 1) ? s[pix + 1]  : 0.f;
        float xu = (i > 0)      ? s[pix - W_] : 0.f;
        float xd = (i < H_ - 1) ? s[pix + W_] : 0.f;
        const float* wc = wOffAll + (c0 + cc) * 56;   // uniform -> s_load
        #pragma unroll
        for (int o = 0; o < 6; ++o) {
            a[o]   = fmaf(xl, wc[3*o],    fmaf(xc, wc[3*o+1],    fmaf(xr, wc[3*o+2],    a[o])));
            a[9+o] = fmaf(xu, wc[27+3*o], fmaf(xc, wc[27+3*o+1], fmaf(xd, wc[27+3*o+2], a[9+o])));
        }
        #pragma unroll
        for (int o = 0; o < 3; ++o) {
            a[6+o]  = fmaf(xl, wc[18+3*o], fmaf(xc, wc[18+3*o+1], fmaf(xr, wc[18+3*o+2], a[6+o])));
            a[15+o] = fmaf(xu, wc[45+3*o], fmaf(xc, wc[45+3*o+1], fmaf(xd, wc[45+3*o+2], a[15+o])));
        }
    }

    // ---- cross-wave reduce: h-set -> LDS (consumed below), v-set -> ws ----
    #pragma unroll
    for (int o = 0; o < 18; ++o) red[wv][o][lane] = a[o];
    __syncthreads();

    for (int v = threadIdx.x; v < 18 * 64; v += 256) {
        int idx = v >> 6;
        int px  = v & 63;
        float sum = red[0][idx][px] + red[1][idx][px]
                  + red[2][idx][px] + red[3][idx][px];
        int pixg = m * 64 + px;
        if (idx < 6) {
            red[0][idx][px] = sum + b_off_h[idx];    // (idx,px) has unique owner
        } else if (idx < 9) {
            red[0][idx][px] = 1.f / (1.f + __expf(-(sum + b_mask_h[idx - 6])));
        } else if (idx < 15) {
            off_v[((size_t)n * 6 + (idx - 9)) * HW_ + pixg] = sum + b_off_v[idx - 9];
        } else {
            mask_v[((size_t)n * 3 + (idx - 15)) * HW_ + pixg] =
                1.f / (1.f + __expf(-(sum + b_mask_v[idx - 15])));
        }
    }
    __syncthreads();

    float dyk[3], dxk[3], mk[3];
    #pragma unroll
    for (int k = 0; k < 3; ++k) {
        dyk[k] = red[0][2*k    ][lane];
        dxk[k] = red[0][2*k + 1][lane];
        mk [k] = red[0][6 + k  ][lane];
    }
    __syncthreads();   // all reads of red done before valT overwrites smem

    // ---- tap setup (horizontal: kyo=0, kxo=k-1) ----
    int b0[3], b1[3];
    float wA0[3], wB0[3], wA1[3], wB1[3];
    #pragma unroll
    for (int k = 0; k < 3; ++k)
        tap_setup((float)i, (float)j, dyk[k], dxk[k], mk[k], 0.f, (float)(k - 1),
                  b0[k], b1[k], wA0[k], wB0[k], wA1[k], wB1[k]);

    // ---- phase 1: paired gathers -> f16 -> LDS ----
    #pragma unroll
    for (int g = 0; g < 2; ++g) {
        half8 t8[3];
        #pragma unroll
        for (int cl = 0; cl < 8; ++cl) {
            const float* s = xs + (g * 8 + cl) * HW_;
            #pragma unroll
            for (int k = 0; k < 3; ++k) {
                f2 p0 = *(const f2*)(s + b0[k]);
                f2 p1 = *(const f2*)(s + b1[k]);
                float v = fmaf(wA0[k], p0.x, fmaf(wB0[k], p0.y,
                          fmaf(wA1[k], p1.x, wB1[k] * p1.y)));
                int t = cl * 3 + k;
                t8[t >> 3][t & 7] = (_Float16)v;
            }
        }
        #pragma unroll
        for (int w = 0; w < 3; ++w)
            *((half8*)&valT[lane][wv * 48 + g * 24 + w * 8]) = t8[w];
    }
    __syncthreads();

    // ---- phase 2: MFMA contraction (round-5 verified layout) ----
    const _Float16* wpA = wF16 + (size_t)(c0 + (lane & 15)) * 192 + ((lane >> 4) << 3);
    half8 A0 = *((const half8*)(wpA +   0));
    half8 A1 = *((const half8*)(wpA +  32));
    half8 A2 = *((const half8*)(wpA +  64));
    half8 A3 = *((const half8*)(wpA +  96));
    half8 A4 = *((const half8*)(wpA + 128));
    half8 A5 = *((const half8*)(wpA + 160));

    int col  = lane & 15;
    int orow = c0 + ((lane >> 4) << 2);
    floatx4 bv = *((const floatx4*)&bias[orow]);
    float* ob = out + ((size_t)n * C_ + orow) * HW_ + m * 64 + col;

#define TILE(T)                                                               \
    {                                                                         \
        const _Float16* bp = &valT[(T) * 16 + col][(lane >> 4) << 3];         \
        floatx4 acc = {0.f, 0.f, 0.f, 0.f};                                   \
        acc = __builtin_amdgcn_mfma_f32_16x16x32_f16(A0, *((const half8*)(bp +   0)), acc, 0, 0, 0); \
        acc = __builtin_amdgcn_mfma_f32_16x16x32_f16(A1, *((const half8*)(bp +  32)), acc, 0, 0, 0); \
        acc = __builtin_amdgcn_mfma_f32_16x16x32_f16(A2, *((const half8*)(bp +  64)), acc, 0, 0, 0); \
        acc = __builtin_amdgcn_mfma_f32_16x16x32_f16(A3, *((const half8*)(bp +  96)), acc, 0, 0, 0); \
        acc = __builtin_amdgcn_mfma_f32_16x16x32_f16(A4, *((const half8*)(bp + 128)), acc, 0, 0, 0); \
        acc = __builtin_amdgcn_mfma_f32_16x16x32_f16(A5, *((const half8*)(bp + 160)), acc, 0, 0, 0); \
        ob[(T) * 16 + (size_t)0 * HW_] = acc[0] + bv[0];                      \
        ob[(T) * 16 + (size_t)1 * HW_] = acc[1] + bv[1];                      \
        ob[(T) * 16 + (size_t)2 * HW_] = acc[2] + bv[2];                      \
        ob[(T) * 16 + (size_t)3 * HW_] = acc[3] + bv[3];                      \
    }

    TILE(0)
    TILE(1)
    TILE(2)
    TILE(3)
#undef TILE
}

// ---------------------------------------------------------------------------
// Vertical pass: deformable (K,1) conv on x_h; offsets/masks precomputed.
// Same swizzle (x_h layout identical to x).
// ---------------------------------------------------------------------------
__global__ __launch_bounds__(256, 4) void deform_v_kernel(
    const float* __restrict__ src, const float* __restrict__ off,
    const float* __restrict__ mask, const _Float16* __restrict__ wF16,
    const float* __restrict__ bias, float* __restrict__ out)
{
    __shared__ __align__(16) _Float16 valT[64][200];

    int lane = threadIdx.x & 63;
    int wv   = threadIdx.x >> 6;
    int c0 = __builtin_amdgcn_readfirstlane(wv << 4);

    SWIZZLE_NP();

    int b0[3], b1[3];
    float wA0[3], wB0[3], wA1[3], wB1[3];
    #pragma unroll
    for (int k = 0; k < 3; ++k) {
        float dy = off[(((size_t)n * 3 + k) * 2 + 0) * HW_ + pix];
        float dx = off[(((size_t)n * 3 + k) * 2 + 1) * HW_ + pix];
        float m_ = mask[((size_t)n * 3 + k) * HW_ + pix];
        tap_setup((float)i, (float)j, dy, dx, m_, (float)(k - 1), 0.f,
                  b0[k], b1[k], wA0[k], wB0[k], wA1[k], wB1[k]);
    }

    const float* sb = src + (size_t)n * C_ * HW_ + (size_t)c0 * HW_;
    #pragma unroll
    for (int g = 0; g < 2; ++g) {
        half8 t8[3];
        #pragma unroll
        for (int cl = 0; cl < 8; ++cl) {
            const float* s = sb + (g * 8 + cl) * HW_;
            #pragma unroll
            for (int k = 0; k < 3; ++k) {
                f2 p0 = *(const f2*)(s + b0[k]);
                f2 p1 = *(const f2*)(s + b1[k]);
                float v = fmaf(wA0[k], p0.x, fmaf(wB0[k], p0.y,
                          fmaf(wA1[k], p1.x, wB1[k] * p1.y)));
                int t = cl * 3 + k;
                t8[t >> 3][t & 7] = (_Float16)v;
            }
        }
        #pragma unroll
        for (int w = 0; w < 3; ++w)
            *((half8*)&valT[lane][wv * 48 + g * 24 + w * 8]) = t8[w];
    }
    __syncthreads();

    const _Float16* wpA = wF16 + (size_t)(c0 + (lane & 15)) * 192 + ((lane >> 4) << 3);
    half8 A0 = *((const half8*)(wpA +   0));
    half8 A1 = *((const half8*)(wpA +  32));
    half8 A2 = *((const half8*)(wpA +  64));
    half8 A3 = *((const half8*)(wpA +  96));
    half8 A4 = *((const half8*)(wpA + 128));
    half8 A5 = *((const half8*)(wpA + 160));

    int col  = lane & 15;
    int orow = c0 + ((lane >> 4) << 2);
    floatx4 bv = *((const floatx4*)&bias[orow]);
    float* ob = out + ((size_t)n * C_ + orow) * HW_ + m * 64 + col;

#define TILE(T)                                                               \
    {                                                                         \
        const _Float16* bp = &valT[(T) * 16 + col][(lane >> 4) << 3];         \
        floatx4 acc = {0.f, 0.f, 0.f, 0.f};                                   \
        acc = __builtin_amdgcn_mfma_f32_16x16x32_f16(A0, *((const half8*)(bp +   0)), acc, 0, 0, 0); \
        acc = __builtin_amdgcn_mfma_f32_16x16x32_f16(A1, *((const half8*)(bp +  32)), acc, 0, 0, 0); \
        acc = __builtin_amdgcn_mfma_f32_16x16x32_f16(A2, *((const half8*)(bp +  64)), acc, 0, 0, 0); \
        acc = __builtin_amdgcn_mfma_f32_16x16x32_f16(A3, *((const half8*)(bp +  96)), acc, 0, 0, 0); \
        acc = __builtin_amdgcn_mfma_f32_16x16x32_f16(A4, *((const half8*)(bp + 128)), acc, 0, 0, 0); \
        acc = __builtin_amdgcn_mfma_f32_16x16x32_f16(A5, *((const half8*)(bp + 160)), acc, 0, 0, 0); \
        ob[(T) * 16 + (size_t)0 * HW_] = acc[0] + bv[0];                      \
        ob[(T) * 16 + (size_t)1 * HW_] = acc[1] + bv[1];                      \
        ob[(T) * 16 + (size_t)2 * HW_] = acc[2] + bv[2];                      \
        ob[(T) * 16 + (size_t)3 * HW_] = acc[3] + bv[3];                      \
    }

    TILE(0)
    TILE(1)
    TILE(2)
    TILE(3)
#undef TILE
}

// ---------------------------------------------------------------------------
extern "C" void kernel_launch(void* const* d_in, const int* in_sizes, int n_in,
                              void* d_out, int out_size, void* d_ws, size_t ws_size,
                              hipStream_t stream)
{
    const float* x        = (const float*)d_in[0];
    const float* w_off_h  = (const float*)d_in[1];
    const float* b_off_h  = (const float*)d_in[2];
    const float* w_mask_h = (const float*)d_in[3];
    const float* b_mask_h = (const float*)d_in[4];
    const float* w_off_v  = (const float*)d_in[5];
    const float* b_off_v  = (const float*)d_in[6];
    const float* w_mask_v = (const float*)d_in[7];
    const float* b_mask_v = (const float*)d_in[8];
    const float* w_h      = (const float*)d_in[9];
    const float* b_h      = (const float*)d_in[10];
    const float* w_v      = (const float*)d_in[11];
    const float* b_v      = (const float*)d_in[12];

    float* ws      = (float*)d_ws;
    float* off_v   = ws;                    // 786432
    float* mask_v  = off_v  + 786432;       // 393216
    float* x_h     = mask_v + 393216;       // 8388608
    float* wOffAll = x_h    + 8388608;      // 3584
    _Float16* wF16_h = (_Float16*)(wOffAll + 3584);  // 12288 halfs
    _Float16* wF16_v = wF16_h + 12288;               // 12288 halfs

    prep_kernel<<<110, 256, 0, stream>>>(
        w_off_h, w_mask_h, w_off_v, w_mask_v, w_h, w_v,
        wOffAll, wF16_h, wF16_v);

    dim3 grid(NPIX / 64), block(256);
    deform_h_kernel<<<grid, block, 0, stream>>>(
        x, wOffAll, b_off_h, b_mask_h, b_off_v, b_mask_v,
        wF16_h, b_h, off_v, mask_v, x_h);

    deform_v_kernel<<<grid, block, 0, stream>>>(
        x_h, off_v, mask_v, wF16_v, b_v, (float*)d_out);
}